// Round 1
// baseline (4004.900 us; speedup 1.0000x reference)
//
#include <hip/hip_runtime.h>
#include <math.h>

#define NN 100000
#define EE 3200000
#define NCH 32

// ---------------- setup kernels ----------------

__global__ void zero_i32_k(int* __restrict__ p, int n) {
  int i = blockIdx.x * blockDim.x + threadIdx.x;
  if (i < n) p[i] = 0;
}

__global__ void hist_k(const int* __restrict__ ei, int* __restrict__ cnt) {
  int e = blockIdx.x * blockDim.x + threadIdx.x;
  if (e >= EE) return;
  int r = ei[e], c = ei[EE + e];
  if (r != c) atomicAdd(&cnt[r], 1);
}

// exclusive scan within blocks of 1024; writes per-block totals
__global__ void scan_block_k(const int* __restrict__ in, int* __restrict__ excl,
                             int* __restrict__ bsums, int n) {
  __shared__ int s[1024];
  int tid = threadIdx.x;
  int i = blockIdx.x * 1024 + tid;
  int v = (i < n) ? in[i] : 0;
  s[tid] = v;
  __syncthreads();
  for (int d = 1; d < 1024; d <<= 1) {
    int t = (tid >= d) ? s[tid - d] : 0;
    __syncthreads();
    s[tid] += t;
    __syncthreads();
  }
  if (i < n) excl[i] = s[tid] - v;
  if (tid == 1023) bsums[blockIdx.x] = s[1023];
}

__global__ void finalize_k(const int* __restrict__ cnt, int* __restrict__ rp,
                           int* __restrict__ cursor, const int* __restrict__ boffs,
                           float* __restrict__ dinv) {
  int i = blockIdx.x * blockDim.x + threadIdx.x;
  if (i >= NN) return;
  int v = rp[i] + boffs[i >> 10];
  rp[i] = v;
  cursor[i] = v;
  int c = cnt[i];
  dinv[i] = (c > 0) ? rsqrtf((float)c) : 0.f;
  if (i == NN - 1) rp[NN] = v + c;
}

__global__ void fill_k(const int* __restrict__ ei, int* __restrict__ cursor,
                       int* __restrict__ colc) {
  int e = blockIdx.x * blockDim.x + threadIdx.x;
  if (e >= EE) return;
  int r = ei[e], c = ei[EE + e];
  if (r != c) {
    int p = atomicAdd(&cursor[r], 1);
    colc[p] = c;
  }
}

// ---------------- layer kernels ----------------

// acc = in(N x 32) @ W(32 x 32)
__global__ __launch_bounds__(256) void gemm_k0_f32_k(const float* __restrict__ in,
                                                     const float* __restrict__ W,
                                                     float* __restrict__ acc) {
  __shared__ float Wl[NCH * NCH];
  for (int t = threadIdx.x; t < NCH * NCH; t += 256) Wl[t] = W[t];
  __syncthreads();
  int t = blockIdx.x * blockDim.x + threadIdx.x;
  if (t >= NN * NCH) return;
  int i = t >> 5, j = t & 31;
  const float* bi = in + i * NCH;
  float g = 0.f;
#pragma unroll
  for (int c = 0; c < NCH; ++c) g = fmaf(bi[c], Wl[c * NCH + j], g);
  acc[t] = g;
}

// acc = x(N x 3) @ W(3 x 32)
__global__ __launch_bounds__(256) void gemm_k0_f3_k(const float* __restrict__ x,
                                                    const float* __restrict__ W,
                                                    float* __restrict__ acc) {
  __shared__ float Wl[96];
  if (threadIdx.x < 96) Wl[threadIdx.x] = W[threadIdx.x];
  __syncthreads();
  int t = blockIdx.x * blockDim.x + threadIdx.x;
  if (t >= NN * NCH) return;
  int i = t >> 5, j = t & 31;
  float g = fmaf(x[i * 3 + 0], Wl[j],
           fmaf(x[i * 3 + 1], Wl[32 + j], x[i * 3 + 2] * Wl[64 + j]));
  acc[t] = g;
}

// One wave per row. Computes C = (FIRST ? L(B) : 2*L(B) - A); acc += C @ Wk.
template <bool FIRST>
__global__ __launch_bounds__(256) void cheb_f32_k(
    const int* __restrict__ rp, const int* __restrict__ colc,
    const float* __restrict__ dinv, const float* __restrict__ B,
    const float* __restrict__ A, float* __restrict__ C, float* __restrict__ acc,
    const float* __restrict__ Wk) {
  __shared__ float Wl[NCH * NCH];
  for (int t = threadIdx.x; t < NCH * NCH; t += 256) Wl[t] = Wk[t];
  __syncthreads();
  int tid = threadIdx.x;
  int wid = tid >> 6, lane = tid & 63;
  int c = lane & 31, h = lane >> 5;
  int nwaves = gridDim.x * 4;
  for (int i = blockIdx.x * 4 + wid; i < NN; i += nwaves) {
    int s = rp[i], e = rp[i + 1];
    float sr = -dinv[i];
    float av = 0.f;
    for (int base = s; base < e; base += 64) {
      int idx = base + lane;
      int cl = 0;
      float dl = 0.f;
      if (idx < e) {
        cl = colc[idx];
        dl = dinv[cl];
      }
      int m = e - base;
      if (m > 64) m = 64;
      for (int jj = 0; jj < m; jj += 2) {
        int j = jj + h;
        int cj = __shfl(cl, j);
        float dj = __shfl(dl, j);
        if (j < m) av = fmaf(dj * sr, B[cj * NCH + c], av);
      }
    }
    av += __shfl_down(av, 32);  // lanes 0..31 now hold full channel sums
    float vw;
    if (FIRST) {
      vw = av;
    } else {
      vw = fmaf(2.f, av, -A[i * NCH + c]);  // valid on lanes<32; hi lanes garbage (unused as src)
    }
    if (h == 0) C[i * NCH + c] = vw;
    // fused acc += v @ Wk ; split the 32-long dot across the two halves
    float g = 0.f;
    int c0 = h << 4;
#pragma unroll
    for (int t = 0; t < 16; ++t)
      g = fmaf(__shfl(vw, c0 + t), Wl[(c0 + t) * NCH + c], g);
    g += __shfl_down(g, 32);
    if (h == 0) acc[i * NCH + c] += g;
  }
}

// One thread per row, F=3. C = (FIRST ? L(B) : 2*L(B) - A); acc += C @ Wk(3x32).
template <bool FIRST>
__global__ __launch_bounds__(256) void cheb_f3_k(
    const int* __restrict__ rp, const int* __restrict__ colc,
    const float* __restrict__ dinv, const float* __restrict__ B,
    const float* __restrict__ A, float* __restrict__ C, float* __restrict__ acc,
    const float* __restrict__ Wk) {
  __shared__ float Wl[96];
  if (threadIdx.x < 96) Wl[threadIdx.x] = Wk[threadIdx.x];
  __syncthreads();
  int i0 = blockIdx.x * blockDim.x + threadIdx.x;
  int stride = gridDim.x * blockDim.x;
  for (int i = i0; i < NN; i += stride) {
    int s = rp[i], e = rp[i + 1];
    float sr = -dinv[i];
    float a0 = 0.f, a1 = 0.f, a2 = 0.f;
    for (int t = s; t < e; ++t) {
      int cc = colc[t];
      float w = dinv[cc] * sr;
      a0 = fmaf(w, B[cc * 3 + 0], a0);
      a1 = fmaf(w, B[cc * 3 + 1], a1);
      a2 = fmaf(w, B[cc * 3 + 2], a2);
    }
    float v0, v1, v2;
    if (FIRST) {
      v0 = a0; v1 = a1; v2 = a2;
    } else {
      v0 = fmaf(2.f, a0, -A[i * 3 + 0]);
      v1 = fmaf(2.f, a1, -A[i * 3 + 1]);
      v2 = fmaf(2.f, a2, -A[i * 3 + 2]);
    }
    C[i * 3 + 0] = v0;
    C[i * 3 + 1] = v1;
    C[i * 3 + 2] = v2;
    float4* acc4 = (float4*)(acc + (size_t)i * NCH);
#pragma unroll
    for (int q = 0; q < 8; ++q) {
      float4 av = acc4[q];
      av.x = fmaf(v0, Wl[q * 4 + 0], fmaf(v1, Wl[32 + q * 4 + 0], fmaf(v2, Wl[64 + q * 4 + 0], av.x)));
      av.y = fmaf(v0, Wl[q * 4 + 1], fmaf(v1, Wl[32 + q * 4 + 1], fmaf(v2, Wl[64 + q * 4 + 1], av.y)));
      av.z = fmaf(v0, Wl[q * 4 + 2], fmaf(v1, Wl[32 + q * 4 + 2], fmaf(v2, Wl[64 + q * 4 + 2], av.z)));
      av.w = fmaf(v0, Wl[q * 4 + 3], fmaf(v1, Wl[32 + q * 4 + 3], fmaf(v2, Wl[64 + q * 4 + 3], av.w)));
      acc4[q] = av;
    }
  }
}

__global__ __launch_bounds__(256) void silu_k(float* __restrict__ a,
                                              const float* __restrict__ b) {
  int t = blockIdx.x * blockDim.x + threadIdx.x;
  if (t >= NN * NCH) return;
  float v = a[t] + b[t & 31];
  a[t] = v / (1.f + expf(-v));
}

__global__ __launch_bounds__(256) void final_kk(const float* __restrict__ h,
                                                const float* __restrict__ W4,
                                                float* __restrict__ out) {
  __shared__ float Wl[32];
  if (threadIdx.x < 32) Wl[threadIdx.x] = W4[threadIdx.x];
  __syncthreads();
  int i = blockIdx.x * blockDim.x + threadIdx.x;
  if (i >= NN) return;
  const float4* h4 = (const float4*)(h + (size_t)i * NCH);
  float g = 0.f;
#pragma unroll
  for (int q = 0; q < 8; ++q) {
    float4 v = h4[q];
    g += v.x * Wl[q * 4 + 0] + v.y * Wl[q * 4 + 1] + v.z * Wl[q * 4 + 2] +
         v.w * Wl[q * 4 + 3];
  }
  out[i] = g;
}

// ---------------- host ----------------

extern "C" void kernel_launch(void* const* d_in, const int* in_sizes, int n_in,
                              void* d_out, int out_size, void* d_ws, size_t ws_size,
                              hipStream_t stream) {
  const float* x = (const float*)d_in[0];
  const int* ei = (const int*)d_in[1];
  const float* W1 = (const float*)d_in[4];
  const float* b1 = (const float*)d_in[5];
  const float* W2 = (const float*)d_in[6];
  const float* b2 = (const float*)d_in[7];
  const float* W3 = (const float*)d_in[8];
  const float* b3 = (const float*)d_in[9];
  const float* W4 = (const float*)d_in[10];
  float* out = (float*)d_out;

  char* ws = (char*)d_ws;
  size_t off = 0;
  auto alloc = [&](size_t bytes) {
    void* p = ws + off;
    off += (bytes + 255) & ~(size_t)255;
    return p;
  };
  int* cnt = (int*)alloc((size_t)NN * 4);
  int* rp = (int*)alloc(((size_t)NN + 1) * 4);
  int* cursor = (int*)alloc((size_t)NN * 4);
  int* bsums = (int*)alloc(1024 * 4);
  int* boffs = (int*)alloc(1024 * 4);
  float* dinv = (float*)alloc((size_t)NN * 4);
  int* colc = (int*)alloc((size_t)EE * 4);
  float* bufA = (float*)alloc((size_t)NN * NCH * 4);
  float* bufB = (float*)alloc((size_t)NN * NCH * 4);
  float* bufC = (float*)alloc((size_t)NN * NCH * 4);
  float* accA = (float*)alloc((size_t)NN * NCH * 4);
  float* accB = (float*)alloc((size_t)NN * NCH * 4);
  (void)ws_size; (void)in_sizes; (void)n_in; (void)out_size;

  // ---- CSR build ----
  zero_i32_k<<<(NN + 255) / 256, 256, 0, stream>>>(cnt, NN);
  hist_k<<<(EE + 255) / 256, 256, 0, stream>>>(ei, cnt);
  int nb = (NN + 1023) / 1024;  // 98
  scan_block_k<<<nb, 1024, 0, stream>>>(cnt, rp, bsums, NN);
  scan_block_k<<<1, 1024, 0, stream>>>(bsums, boffs, bsums, nb);
  finalize_k<<<(NN + 255) / 256, 256, 0, stream>>>(cnt, rp, cursor, boffs, dinv);
  fill_k<<<(EE + 255) / 256, 256, 0, stream>>>(ei, cursor, colc);

  const int GB = 2048;          // wave-per-row grid (grid-stride)
  const int GE = (NN * NCH + 255) / 256;  // elementwise grids
  const int GR = (NN + 255) / 256;        // row grids

  // ---- layer 1: K=24, F=3 -> 32 ----
  gemm_k0_f3_k<<<GE, 256, 0, stream>>>(x, W1, accA);
  cheb_f3_k<true><<<GR, 256, 0, stream>>>(rp, colc, dinv, x, nullptr, bufA, accA, W1 + 96);
  {
    const float* Ap = x;
    const float* Bp = bufA;
    float* cyc[3] = {bufB, bufC, bufA};
    for (int k = 2; k < 24; ++k) {
      float* Cp = cyc[(k - 2) % 3];
      cheb_f3_k<false><<<GR, 256, 0, stream>>>(rp, colc, dinv, Bp, Ap, Cp, accA, W1 + 96 * k);
      Ap = Bp;
      Bp = Cp;
    }
  }
  silu_k<<<GE, 256, 0, stream>>>(accA, b1);

  // ---- layers 2 & 3: K=12 / K=10, F=32 -> 32 ----
  auto run_layer = [&](const float* in, float* accOut, const float* W,
                       const float* b, int K) {
    gemm_k0_f32_k<<<GE, 256, 0, stream>>>(in, W, accOut);
    cheb_f32_k<true><<<GB, 256, 0, stream>>>(rp, colc, dinv, in, nullptr, bufA, accOut, W + NCH * NCH);
    const float* Ap = in;
    const float* Bp = bufA;
    float* cyc[3] = {bufB, bufC, bufA};
    for (int k = 2; k < K; ++k) {
      float* Cp = cyc[(k - 2) % 3];
      cheb_f32_k<false><<<GB, 256, 0, stream>>>(rp, colc, dinv, Bp, Ap, Cp, accOut, W + (size_t)NCH * NCH * k);
      Ap = Bp;
      Bp = Cp;
    }
    silu_k<<<GE, 256, 0, stream>>>(accOut, b);
  };
  run_layer(accA, accB, W2, b2, 12);
  run_layer(accB, accA, W3, b3, 10);

  // ---- layer 4: K=1, 32 -> 1, no bias ----
  final_kk<<<GR, 256, 0, stream>>>(accA, W4, out);
}

// Round 2
// 3791.540 us; speedup vs baseline: 1.0563x; 1.0563x over previous
//
#include <hip/hip_runtime.h>
#include <math.h>

#define NN 100000
#define EE 3200000
#define NCH 32

typedef unsigned short ushortT;
typedef unsigned int uintT;

__device__ __forceinline__ float b2f(ushortT u) {
  return __uint_as_float(((uintT)u) << 16);
}
__device__ __forceinline__ ushortT f2b(float f) {
  uintT u = __float_as_uint(f);
  uintT r = u + 0x7fffu + ((u >> 16) & 1u);  // round-to-nearest-even
  return (ushortT)(r >> 16);
}

// ---------------- setup kernels ----------------

__global__ void zero_i32_k(int* __restrict__ p, int n) {
  int i = blockIdx.x * blockDim.x + threadIdx.x;
  if (i < n) p[i] = 0;
}

// 4 edges per thread, int4 loads
__global__ void hist_k(const int* __restrict__ ei, int* __restrict__ cnt) {
  int t = blockIdx.x * blockDim.x + threadIdx.x;
  if (t * 4 >= EE) return;
  int4 r4 = ((const int4*)ei)[t];
  int4 c4 = ((const int4*)(ei + EE))[t];
  if (r4.x != c4.x) atomicAdd(&cnt[r4.x], 1);
  if (r4.y != c4.y) atomicAdd(&cnt[r4.y], 1);
  if (r4.z != c4.z) atomicAdd(&cnt[r4.z], 1);
  if (r4.w != c4.w) atomicAdd(&cnt[r4.w], 1);
}

// exclusive scan within blocks of 1024; writes per-block totals
__global__ void scan_block_k(const int* __restrict__ in, int* __restrict__ excl,
                             int* __restrict__ bsums, int n) {
  __shared__ int s[1024];
  int tid = threadIdx.x;
  int i = blockIdx.x * 1024 + tid;
  int v = (i < n) ? in[i] : 0;
  s[tid] = v;
  __syncthreads();
  for (int d = 1; d < 1024; d <<= 1) {
    int t = (tid >= d) ? s[tid - d] : 0;
    __syncthreads();
    s[tid] += t;
    __syncthreads();
  }
  if (i < n) excl[i] = s[tid] - v;
  if (tid == 1023) bsums[blockIdx.x] = s[1023];
}

__global__ void finalize_k(const int* __restrict__ cnt, int* __restrict__ rp,
                           int* __restrict__ cursor, const int* __restrict__ boffs,
                           float* __restrict__ dinv) {
  int i = blockIdx.x * blockDim.x + threadIdx.x;
  if (i >= NN) return;
  int v = rp[i] + boffs[i >> 10];
  rp[i] = v;
  cursor[i] = v;
  int c = cnt[i];
  dinv[i] = (c > 0) ? rsqrtf((float)c) : 0.f;
  if (i == NN - 1) rp[NN] = v + c;
}

__global__ void fill_k(const int* __restrict__ ei, int* __restrict__ cursor,
                       int* __restrict__ colc) {
  int t = blockIdx.x * blockDim.x + threadIdx.x;
  if (t * 4 >= EE) return;
  int4 r4 = ((const int4*)ei)[t];
  int4 c4 = ((const int4*)(ei + EE))[t];
  int p0 = -1, p1 = -1, p2 = -1, p3 = -1;
  if (r4.x != c4.x) p0 = atomicAdd(&cursor[r4.x], 1);
  if (r4.y != c4.y) p1 = atomicAdd(&cursor[r4.y], 1);
  if (r4.z != c4.z) p2 = atomicAdd(&cursor[r4.z], 1);
  if (r4.w != c4.w) p3 = atomicAdd(&cursor[r4.w], 1);
  if (p0 >= 0) colc[p0] = c4.x;
  if (p1 >= 0) colc[p1] = c4.y;
  if (p2 >= 0) colc[p2] = c4.z;
  if (p3 >= 0) colc[p3] = c4.w;
}

// ---------------- layer kernels ----------------

// One thread per row, F=3. C = (FIRST ? L(B) : 2*L(B) - A). fp32 planes.
template <bool FIRST>
__global__ __launch_bounds__(256) void cheb_f3_k(
    const int* __restrict__ rp, const int* __restrict__ colc,
    const float* __restrict__ dinv, const float* __restrict__ B,
    const float* __restrict__ A, float* __restrict__ C) {
  int i = blockIdx.x * blockDim.x + threadIdx.x;
  if (i >= NN) return;
  int s = rp[i], e = rp[i + 1];
  float sr = -dinv[i];
  float a0 = 0.f, a1 = 0.f, a2 = 0.f;
  for (int t = s; t < e; ++t) {
    int cc = colc[t];
    float w = dinv[cc] * sr;
    a0 = fmaf(w, B[cc * 3 + 0], a0);
    a1 = fmaf(w, B[cc * 3 + 1], a1);
    a2 = fmaf(w, B[cc * 3 + 2], a2);
  }
  if (FIRST) {
    C[i * 3 + 0] = a0;
    C[i * 3 + 1] = a1;
    C[i * 3 + 2] = a2;
  } else {
    C[i * 3 + 0] = fmaf(2.f, a0, -A[i * 3 + 0]);
    C[i * 3 + 1] = fmaf(2.f, a1, -A[i * 3 + 1]);
    C[i * 3 + 2] = fmaf(2.f, a2, -A[i * 3 + 2]);
  }
}

// Layer-1 batched GEMM over all 24 T-planes + bias + SiLU -> bf16 out.
__global__ __launch_bounds__(256) void gemm_l1_k(const float* __restrict__ x,
                                                 const float* __restrict__ Tall,
                                                 const float* __restrict__ W1,
                                                 const float* __restrict__ b1,
                                                 ushortT* __restrict__ h1) {
  __shared__ float Wl[24 * 96];
  for (int t = threadIdx.x; t < 24 * 96; t += 256) Wl[t] = W1[t];
  __syncthreads();
  int t = blockIdx.x * blockDim.x + threadIdx.x;
  if (t >= NN * NCH) return;
  int i = t >> 5, j = t & 31;
  float g = b1[j];
  g = fmaf(x[i * 3 + 0], Wl[j],
      fmaf(x[i * 3 + 1], Wl[32 + j], fmaf(x[i * 3 + 2], Wl[64 + j], g)));
#pragma unroll
  for (int k = 1; k < 24; ++k) {
    const float* Tp = Tall + ((size_t)(k - 1) * NN + i) * 3;
    g = fmaf(Tp[0], Wl[k * 96 + j],
        fmaf(Tp[1], Wl[k * 96 + 32 + j], fmaf(Tp[2], Wl[k * 96 + 64 + j], g)));
  }
  float sv = g / (1.f + expf(-g));
  h1[t] = f2b(sv);
}

// acc = in(N x 32, bf16) @ W(32 x 32, f32)
__global__ __launch_bounds__(256) void gemm_k0_b16_k(const ushortT* __restrict__ in,
                                                     const float* __restrict__ W,
                                                     float* __restrict__ acc) {
  __shared__ float Wl[NCH * NCH];
  for (int t = threadIdx.x; t < NCH * NCH; t += 256) Wl[t] = W[t];
  __syncthreads();
  int t = blockIdx.x * blockDim.x + threadIdx.x;
  if (t >= NN * NCH) return;
  int i = t >> 5, j = t & 31;
  const ushortT* bi = in + (size_t)i * NCH;
  float g = 0.f;
#pragma unroll
  for (int c = 0; c < NCH; ++c) g = fmaf(b2f(bi[c]), Wl[c * NCH + j], g);
  acc[t] = g;
}

// One wave per row, bf16 state. C = (FIRST ? L(B) : 2*L(B) - A); acc += C @ Wk.
template <bool FIRST>
__global__ __launch_bounds__(256) void cheb_b16_k(
    const int* __restrict__ rp, const int* __restrict__ colc,
    const float* __restrict__ dinv, const ushortT* __restrict__ B,
    const ushortT* __restrict__ A, ushortT* __restrict__ C,
    float* __restrict__ acc, const float* __restrict__ Wk) {
  __shared__ float Wl[NCH * NCH];
  for (int t = threadIdx.x; t < NCH * NCH; t += 256) Wl[t] = Wk[t];
  __syncthreads();
  int tid = threadIdx.x;
  int wid = tid >> 6, lane = tid & 63;
  int c = lane & 31, h = lane >> 5;
  int nwaves = gridDim.x * 4;
  for (int i = blockIdx.x * 4 + wid; i < NN; i += nwaves) {
    int s = rp[i], e = rp[i + 1];
    float sr = -dinv[i];
    float av = 0.f;
    for (int base = s; base < e; base += 64) {
      int idx = base + lane;
      int cl = 0;
      float dl = 0.f;
      if (idx < e) {
        cl = colc[idx];
        dl = dinv[cl];
      }
      int m = e - base;
      if (m > 64) m = 64;
      for (int jj = 0; jj < m; jj += 2) {
        int j = jj + h;
        int cj = __shfl(cl, j);
        float dj = __shfl(dl, j);
        if (j < m) av = fmaf(dj * sr, b2f(B[(size_t)cj * NCH + c]), av);
      }
    }
    av += __shfl_down(av, 32);  // lanes 0..31 hold full channel sums
    float vw;
    if (FIRST) {
      vw = av;
    } else {
      vw = fmaf(2.f, av, -b2f(A[(size_t)i * NCH + c]));  // hi lanes garbage (never sourced)
    }
    if (h == 0) C[(size_t)i * NCH + c] = f2b(vw);
    float g = 0.f;
    int c0 = h << 4;
#pragma unroll
    for (int t = 0; t < 16; ++t)
      g = fmaf(__shfl(vw, c0 + t), Wl[(c0 + t) * NCH + c], g);
    g += __shfl_down(g, 32);
    if (h == 0) acc[(size_t)i * NCH + c] += g;
  }
}

__global__ __launch_bounds__(256) void silu_b16_k(const float* __restrict__ a,
                                                  const float* __restrict__ b,
                                                  ushortT* __restrict__ h) {
  int t = blockIdx.x * blockDim.x + threadIdx.x;
  if (t >= NN * NCH) return;
  float v = a[t] + b[t & 31];
  h[t] = f2b(v / (1.f + expf(-v)));
}

__global__ __launch_bounds__(256) void final_kk(const ushortT* __restrict__ h,
                                                const float* __restrict__ W4,
                                                float* __restrict__ out) {
  __shared__ float Wl[32];
  if (threadIdx.x < 32) Wl[threadIdx.x] = W4[threadIdx.x];
  __syncthreads();
  int i = blockIdx.x * blockDim.x + threadIdx.x;
  if (i >= NN) return;
  const ushortT* hr = h + (size_t)i * NCH;
  float g = 0.f;
#pragma unroll
  for (int c = 0; c < NCH; ++c) g = fmaf(b2f(hr[c]), Wl[c], g);
  out[i] = g;
}

// ---------------- host ----------------

extern "C" void kernel_launch(void* const* d_in, const int* in_sizes, int n_in,
                              void* d_out, int out_size, void* d_ws, size_t ws_size,
                              hipStream_t stream) {
  const float* x = (const float*)d_in[0];
  const int* ei = (const int*)d_in[1];
  const float* W1 = (const float*)d_in[4];
  const float* b1 = (const float*)d_in[5];
  const float* W2 = (const float*)d_in[6];
  const float* b2 = (const float*)d_in[7];
  const float* W3 = (const float*)d_in[8];
  const float* b3 = (const float*)d_in[9];
  const float* W4 = (const float*)d_in[10];
  float* out = (float*)d_out;

  char* ws = (char*)d_ws;
  size_t off = 0;
  auto alloc = [&](size_t bytes) {
    void* p = ws + off;
    off += (bytes + 255) & ~(size_t)255;
    return p;
  };
  int* cnt = (int*)alloc((size_t)NN * 4);
  int* rp = (int*)alloc(((size_t)NN + 1) * 4);
  int* cursor = (int*)alloc((size_t)NN * 4);
  int* bsums = (int*)alloc(1024 * 4);
  int* boffs = (int*)alloc(1024 * 4);
  float* dinv = (float*)alloc((size_t)NN * 4);
  int* colc = (int*)alloc((size_t)EE * 4);
  float* Tall = (float*)alloc((size_t)23 * NN * 3 * 4);   // planes k=1..23
  ushortT* tA = (ushortT*)alloc((size_t)NN * NCH * 2);
  ushortT* tB = (ushortT*)alloc((size_t)NN * NCH * 2);
  ushortT* tC = (ushortT*)alloc((size_t)NN * NCH * 2);
  ushortT* h1 = (ushortT*)alloc((size_t)NN * NCH * 2);
  ushortT* h2 = (ushortT*)alloc((size_t)NN * NCH * 2);
  ushortT* h3 = (ushortT*)alloc((size_t)NN * NCH * 2);
  float* acc = (float*)alloc((size_t)NN * NCH * 4);
  (void)ws_size; (void)in_sizes; (void)n_in; (void)out_size;

  // ---- CSR build ----
  zero_i32_k<<<(NN + 255) / 256, 256, 0, stream>>>(cnt, NN);
  hist_k<<<(EE / 4 + 255) / 256, 256, 0, stream>>>(ei, cnt);
  int nb = (NN + 1023) / 1024;  // 98
  scan_block_k<<<nb, 1024, 0, stream>>>(cnt, rp, bsums, NN);
  scan_block_k<<<1, 1024, 0, stream>>>(bsums, boffs, bsums, nb);
  finalize_k<<<(NN + 255) / 256, 256, 0, stream>>>(cnt, rp, cursor, boffs, dinv);
  fill_k<<<(EE / 4 + 255) / 256, 256, 0, stream>>>(ei, cursor, colc);

  const int GB = 2048;                    // wave-per-row grid (grid-stride)
  const int GE = (NN * NCH + 255) / 256;  // elementwise grids
  const int GR = (NN + 255) / 256;        // row grids

  auto Tp = [&](int k) { return Tall + (size_t)(k - 1) * NN * 3; };

  // ---- layer 1: K=24, F=3 -> 32 ----
  cheb_f3_k<true><<<GR, 256, 0, stream>>>(rp, colc, dinv, x, nullptr, Tp(1));
  for (int k = 2; k < 24; ++k) {
    const float* Ap = (k == 2) ? x : Tp(k - 2);
    cheb_f3_k<false><<<GR, 256, 0, stream>>>(rp, colc, dinv, Tp(k - 1), Ap, Tp(k));
  }
  gemm_l1_k<<<GE, 256, 0, stream>>>(x, Tall, W1, b1, h1);

  // ---- layers 2 & 3: K=12 / K=10, F=32 -> 32, bf16 state ----
  auto run_layer = [&](const ushortT* in, ushortT* hout, const float* W,
                       const float* b, int K) {
    gemm_k0_b16_k<<<GE, 256, 0, stream>>>(in, W, acc);
    cheb_b16_k<true><<<GB, 256, 0, stream>>>(rp, colc, dinv, in, nullptr, tA, acc,
                                             W + NCH * NCH);
    const ushortT* Ap = in;
    const ushortT* Bp = tA;
    ushortT* cyc[3] = {tB, tC, tA};
    for (int k = 2; k < K; ++k) {
      ushortT* Cp = cyc[(k - 2) % 3];
      cheb_b16_k<false><<<GB, 256, 0, stream>>>(rp, colc, dinv, Bp, Ap, Cp, acc,
                                                W + (size_t)NCH * NCH * k);
      Ap = Bp;
      Bp = Cp;
    }
    silu_b16_k<<<GE, 256, 0, stream>>>(acc, b, hout);
  };
  run_layer(h1, h2, W2, b2, 12);
  run_layer(h2, h3, W3, b3, 10);

  // ---- layer 4: K=1, 32 -> 1, no bias ----
  final_kk<<<GR, 256, 0, stream>>>(h3, W4, out);
}

// Round 3
// 2608.880 us; speedup vs baseline: 1.5351x; 1.4533x over previous
//
#include <hip/hip_runtime.h>
#include <math.h>

#define NN 100000
#define EE 3200000
#define NCH 32
#define FILL_PASSES 8

typedef unsigned short ushortT;
typedef unsigned int uintT;

__device__ __forceinline__ float b2f(ushortT u) {
  return __uint_as_float(((uintT)u) << 16);
}
__device__ __forceinline__ ushortT f2b(float f) {
  uintT u = __float_as_uint(f);
  uintT r = u + 0x7fffu + ((u >> 16) & 1u);  // round-to-nearest-even
  return (ushortT)(r >> 16);
}

// ---------------- setup kernels ----------------

__global__ void zero_i32_k(int* __restrict__ p, int n) {
  int i = blockIdx.x * blockDim.x + threadIdx.x;
  if (i < n) p[i] = 0;
}

// 4 edges per thread, int4 loads
__global__ void hist_k(const int* __restrict__ ei, int* __restrict__ cnt) {
  int t = blockIdx.x * blockDim.x + threadIdx.x;
  if (t * 4 >= EE) return;
  int4 r4 = ((const int4*)ei)[t];
  int4 c4 = ((const int4*)(ei + EE))[t];
  if (r4.x != c4.x) atomicAdd(&cnt[r4.x], 1);
  if (r4.y != c4.y) atomicAdd(&cnt[r4.y], 1);
  if (r4.z != c4.z) atomicAdd(&cnt[r4.z], 1);
  if (r4.w != c4.w) atomicAdd(&cnt[r4.w], 1);
}

// exclusive scan within blocks of 1024; writes per-block totals
__global__ void scan_block_k(const int* __restrict__ in, int* __restrict__ excl,
                             int* __restrict__ bsums, int n) {
  __shared__ int s[1024];
  int tid = threadIdx.x;
  int i = blockIdx.x * 1024 + tid;
  int v = (i < n) ? in[i] : 0;
  s[tid] = v;
  __syncthreads();
  for (int d = 1; d < 1024; d <<= 1) {
    int t = (tid >= d) ? s[tid - d] : 0;
    __syncthreads();
    s[tid] += t;
    __syncthreads();
  }
  if (i < n) excl[i] = s[tid] - v;
  if (tid == 1023) bsums[blockIdx.x] = s[1023];
}

__global__ void finalize_k(const int* __restrict__ cnt, int* __restrict__ rp,
                           int* __restrict__ cursor, const int* __restrict__ boffs,
                           float* __restrict__ dinv) {
  int i = blockIdx.x * blockDim.x + threadIdx.x;
  if (i >= NN) return;
  int v = rp[i] + boffs[i >> 10];
  rp[i] = v;
  cursor[i] = v;
  int c = cnt[i];
  dinv[i] = (c > 0) ? rsqrtf((float)c) : 0.f;
  if (i == NN - 1) rp[NN] = v + c;
}

// windowed scatter: only rows in [lo,hi) handled this pass -> colc writes land
// in a ~1.6MB window that stays L2-resident, lines fill fully before eviction.
__global__ void fill_k(const int* __restrict__ ei, int* __restrict__ cursor,
                       int* __restrict__ colc, int lo, int hi) {
  int t = blockIdx.x * blockDim.x + threadIdx.x;
  if (t * 4 >= EE) return;
  int4 r4 = ((const int4*)ei)[t];
  int4 c4 = ((const int4*)(ei + EE))[t];
  if (r4.x != c4.x && r4.x >= lo && r4.x < hi) colc[atomicAdd(&cursor[r4.x], 1)] = c4.x;
  if (r4.y != c4.y && r4.y >= lo && r4.y < hi) colc[atomicAdd(&cursor[r4.y], 1)] = c4.y;
  if (r4.z != c4.z && r4.z >= lo && r4.z < hi) colc[atomicAdd(&cursor[r4.z], 1)] = c4.z;
  if (r4.w != c4.w && r4.w >= lo && r4.w < hi) colc[atomicAdd(&cursor[r4.w], 1)] = c4.w;
}

// ---------------- layer kernels ----------------

// One thread per row, F=3, x4 ILP unroll. C = (FIRST ? L(B) : 2*L(B) - A).
template <bool FIRST>
__global__ __launch_bounds__(256) void cheb_f3_k(
    const int* __restrict__ rp, const int* __restrict__ colc,
    const float* __restrict__ dinv, const float* __restrict__ B,
    const float* __restrict__ A, float* __restrict__ C) {
  int i = blockIdx.x * blockDim.x + threadIdx.x;
  if (i >= NN) return;
  int s = rp[i], e = rp[i + 1];
  float a0 = 0.f, a1 = 0.f, a2 = 0.f;
  int t = s;
  for (; t + 4 <= e; t += 4) {
    int c0 = colc[t], c1 = colc[t + 1], c2 = colc[t + 2], c3 = colc[t + 3];
    float w0 = dinv[c0], w1 = dinv[c1], w2 = dinv[c2], w3 = dinv[c3];
    const float* p0 = B + c0 * 3;
    const float* p1 = B + c1 * 3;
    const float* p2 = B + c2 * 3;
    const float* p3 = B + c3 * 3;
    a0 = fmaf(w0, p0[0], a0); a1 = fmaf(w0, p0[1], a1); a2 = fmaf(w0, p0[2], a2);
    a0 = fmaf(w1, p1[0], a0); a1 = fmaf(w1, p1[1], a1); a2 = fmaf(w1, p1[2], a2);
    a0 = fmaf(w2, p2[0], a0); a1 = fmaf(w2, p2[1], a1); a2 = fmaf(w2, p2[2], a2);
    a0 = fmaf(w3, p3[0], a0); a1 = fmaf(w3, p3[1], a1); a2 = fmaf(w3, p3[2], a2);
  }
  for (; t < e; ++t) {
    int cc = colc[t];
    float w = dinv[cc];
    a0 = fmaf(w, B[cc * 3 + 0], a0);
    a1 = fmaf(w, B[cc * 3 + 1], a1);
    a2 = fmaf(w, B[cc * 3 + 2], a2);
  }
  float sr = -dinv[i];
  a0 *= sr; a1 *= sr; a2 *= sr;
  if (FIRST) {
    C[i * 3 + 0] = a0;
    C[i * 3 + 1] = a1;
    C[i * 3 + 2] = a2;
  } else {
    C[i * 3 + 0] = fmaf(2.f, a0, -A[i * 3 + 0]);
    C[i * 3 + 1] = fmaf(2.f, a1, -A[i * 3 + 1]);
    C[i * 3 + 2] = fmaf(2.f, a2, -A[i * 3 + 2]);
  }
}

// Layer-1 batched GEMM over all 24 T-planes + bias + SiLU -> bf16 out.
__global__ __launch_bounds__(256) void gemm_l1_k(const float* __restrict__ x,
                                                 const float* __restrict__ Tall,
                                                 const float* __restrict__ W1,
                                                 const float* __restrict__ b1,
                                                 ushortT* __restrict__ h1) {
  __shared__ float Wl[24 * 96];
  for (int t = threadIdx.x; t < 24 * 96; t += 256) Wl[t] = W1[t];
  __syncthreads();
  int t = blockIdx.x * blockDim.x + threadIdx.x;
  if (t >= NN * NCH) return;
  int i = t >> 5, j = t & 31;
  float g = b1[j];
  g = fmaf(x[i * 3 + 0], Wl[j],
      fmaf(x[i * 3 + 1], Wl[32 + j], fmaf(x[i * 3 + 2], Wl[64 + j], g)));
#pragma unroll
  for (int k = 1; k < 24; ++k) {
    const float* Tp = Tall + ((size_t)(k - 1) * NN + i) * 3;
    g = fmaf(Tp[0], Wl[k * 96 + j],
        fmaf(Tp[1], Wl[k * 96 + 32 + j], fmaf(Tp[2], Wl[k * 96 + 64 + j], g)));
  }
  float sv = g / (1.f + expf(-g));
  h1[t] = f2b(sv);
}

// acc = in(N x 32, bf16) @ W(32 x 32, f32)
__global__ __launch_bounds__(256) void gemm_k0_b16_k(const ushortT* __restrict__ in,
                                                     const float* __restrict__ W,
                                                     float* __restrict__ acc) {
  __shared__ float Wl[NCH * NCH];
  for (int t = threadIdx.x; t < NCH * NCH; t += 256) Wl[t] = W[t];
  __syncthreads();
  int t = blockIdx.x * blockDim.x + threadIdx.x;
  if (t >= NN * NCH) return;
  int i = t >> 5, j = t & 31;
  const ushortT* bi = in + (size_t)i * NCH;
  float g = 0.f;
#pragma unroll
  for (int c = 0; c < NCH; ++c) g = fmaf(b2f(bi[c]), Wl[c * NCH + j], g);
  acc[t] = g;
}

// One wave per row, bf16 state. C = (FIRST ? L(B) : 2*L(B) - A); acc += C @ Wk.
// Masked lanes carry dl=0 so the edge loop needs no per-edge predicate.
template <bool FIRST>
__global__ __launch_bounds__(256) void cheb_b16_k(
    const int* __restrict__ rp, const int* __restrict__ colc,
    const float* __restrict__ dinv, const ushortT* __restrict__ B,
    const ushortT* __restrict__ A, ushortT* __restrict__ C,
    float* __restrict__ acc, const float* __restrict__ Wk) {
  __shared__ float Wl[NCH * NCH];
  for (int t = threadIdx.x; t < NCH * NCH; t += 256) Wl[t] = Wk[t];
  __syncthreads();
  int tid = threadIdx.x;
  int wid = tid >> 6, lane = tid & 63;
  int c = lane & 31, h = lane >> 5;
  int nwaves = gridDim.x * 4;
  for (int i = blockIdx.x * 4 + wid; i < NN; i += nwaves) {
    int s = rp[i], e = rp[i + 1];
    float av = 0.f;
    for (int base = s; base < e; base += 64) {
      int idx = base + lane;
      int cl = 0;
      float dl = 0.f;
      if (idx < e) {
        cl = colc[idx];
        dl = dinv[cl];
      }
      int m = e - base;
      if (m > 64) m = 64;
      int jj = 0;
      for (; jj + 8 <= m; jj += 8) {
#pragma unroll
        for (int q = 0; q < 8; q += 2) {
          int j = jj + q + h;
          int cj = __shfl(cl, j);
          float dj = __shfl(dl, j);
          av = fmaf(dj, b2f(B[(size_t)cj * NCH + c]), av);
        }
      }
      for (; jj < m; jj += 2) {
        int j = jj + h;  // if j >= m, dj==0 -> contributes nothing
        int cj = __shfl(cl, j);
        float dj = __shfl(dl, j);
        av = fmaf(dj, b2f(B[(size_t)cj * NCH + c]), av);
      }
    }
    av += __shfl_down(av, 32);  // lanes 0..31 hold full channel sums
    av *= -dinv[i];             // common row factor applied once
    float vw;
    if (FIRST) {
      vw = av;
    } else {
      vw = fmaf(2.f, av, -b2f(A[(size_t)i * NCH + c]));  // hi lanes garbage (never sourced)
    }
    if (h == 0) C[(size_t)i * NCH + c] = f2b(vw);
    float g = 0.f;
    int c0 = h << 4;
#pragma unroll
    for (int t = 0; t < 16; ++t)
      g = fmaf(__shfl(vw, c0 + t), Wl[(c0 + t) * NCH + c], g);
    g += __shfl_down(g, 32);
    if (h == 0) acc[(size_t)i * NCH + c] += g;
  }
}

__global__ __launch_bounds__(256) void silu_b16_k(const float* __restrict__ a,
                                                  const float* __restrict__ b,
                                                  ushortT* __restrict__ h) {
  int t = blockIdx.x * blockDim.x + threadIdx.x;
  if (t >= NN * NCH) return;
  float v = a[t] + b[t & 31];
  h[t] = f2b(v / (1.f + expf(-v)));
}

__global__ __launch_bounds__(256) void final_kk(const ushortT* __restrict__ h,
                                                const float* __restrict__ W4,
                                                float* __restrict__ out) {
  __shared__ float Wl[32];
  if (threadIdx.x < 32) Wl[threadIdx.x] = W4[threadIdx.x];
  __syncthreads();
  int i = blockIdx.x * blockDim.x + threadIdx.x;
  if (i >= NN) return;
  const ushortT* hr = h + (size_t)i * NCH;
  float g = 0.f;
#pragma unroll
  for (int c = 0; c < NCH; ++c) g = fmaf(b2f(hr[c]), Wl[c], g);
  out[i] = g;
}

// ---------------- host ----------------

extern "C" void kernel_launch(void* const* d_in, const int* in_sizes, int n_in,
                              void* d_out, int out_size, void* d_ws, size_t ws_size,
                              hipStream_t stream) {
  const float* x = (const float*)d_in[0];
  const int* ei = (const int*)d_in[1];
  const float* W1 = (const float*)d_in[4];
  const float* b1 = (const float*)d_in[5];
  const float* W2 = (const float*)d_in[6];
  const float* b2 = (const float*)d_in[7];
  const float* W3 = (const float*)d_in[8];
  const float* b3 = (const float*)d_in[9];
  const float* W4 = (const float*)d_in[10];
  float* out = (float*)d_out;

  char* ws = (char*)d_ws;
  size_t off = 0;
  auto alloc = [&](size_t bytes) {
    void* p = ws + off;
    off += (bytes + 255) & ~(size_t)255;
    return p;
  };
  int* cnt = (int*)alloc((size_t)NN * 4);
  int* rp = (int*)alloc(((size_t)NN + 1) * 4);
  int* cursor = (int*)alloc((size_t)NN * 4);
  int* bsums = (int*)alloc(1024 * 4);
  int* boffs = (int*)alloc(1024 * 4);
  float* dinv = (float*)alloc((size_t)NN * 4);
  int* colc = (int*)alloc((size_t)EE * 4);
  float* Tall = (float*)alloc((size_t)23 * NN * 3 * 4);   // planes k=1..23
  ushortT* tA = (ushortT*)alloc((size_t)NN * NCH * 2);
  ushortT* tB = (ushortT*)alloc((size_t)NN * NCH * 2);
  ushortT* tC = (ushortT*)alloc((size_t)NN * NCH * 2);
  ushortT* h1 = (ushortT*)alloc((size_t)NN * NCH * 2);
  ushortT* h2 = (ushortT*)alloc((size_t)NN * NCH * 2);
  ushortT* h3 = (ushortT*)alloc((size_t)NN * NCH * 2);
  float* acc = (float*)alloc((size_t)NN * NCH * 4);
  (void)ws_size; (void)in_sizes; (void)n_in; (void)out_size;

  // ---- CSR build ----
  zero_i32_k<<<(NN + 255) / 256, 256, 0, stream>>>(cnt, NN);
  hist_k<<<(EE / 4 + 255) / 256, 256, 0, stream>>>(ei, cnt);
  int nb = (NN + 1023) / 1024;  // 98
  scan_block_k<<<nb, 1024, 0, stream>>>(cnt, rp, bsums, NN);
  scan_block_k<<<1, 1024, 0, stream>>>(bsums, boffs, bsums, nb);
  finalize_k<<<(NN + 255) / 256, 256, 0, stream>>>(cnt, rp, cursor, boffs, dinv);
  {
    int step = (NN + FILL_PASSES - 1) / FILL_PASSES;
    for (int p = 0; p < FILL_PASSES; ++p) {
      int lo = p * step;
      int hi = (lo + step < NN) ? lo + step : NN;
      fill_k<<<(EE / 4 + 255) / 256, 256, 0, stream>>>(ei, cursor, colc, lo, hi);
    }
  }

  const int GB = 2048;                    // wave-per-row grid (grid-stride)
  const int GE = (NN * NCH + 255) / 256;  // elementwise grids
  const int GR = (NN + 255) / 256;        // row grids

  auto Tp = [&](int k) { return Tall + (size_t)(k - 1) * NN * 3; };

  // ---- layer 1: K=24, F=3 -> 32 ----
  cheb_f3_k<true><<<GR, 256, 0, stream>>>(rp, colc, dinv, x, nullptr, Tp(1));
  for (int k = 2; k < 24; ++k) {
    const float* Ap = (k == 2) ? x : Tp(k - 2);
    cheb_f3_k<false><<<GR, 256, 0, stream>>>(rp, colc, dinv, Tp(k - 1), Ap, Tp(k));
  }
  gemm_l1_k<<<GE, 256, 0, stream>>>(x, Tall, W1, b1, h1);

  // ---- layers 2 & 3: K=12 / K=10, F=32 -> 32, bf16 state ----
  auto run_layer = [&](const ushortT* in, ushortT* hout, const float* W,
                       const float* b, int K) {
    gemm_k0_b16_k<<<GE, 256, 0, stream>>>(in, W, acc);
    cheb_b16_k<true><<<GB, 256, 0, stream>>>(rp, colc, dinv, in, nullptr, tA, acc,
                                             W + NCH * NCH);
    const ushortT* Ap = in;
    const ushortT* Bp = tA;
    ushortT* cyc[3] = {tB, tC, tA};
    for (int k = 2; k < K; ++k) {
      ushortT* Cp = cyc[(k - 2) % 3];
      cheb_b16_k<false><<<GB, 256, 0, stream>>>(rp, colc, dinv, Bp, Ap, Cp, acc,
                                                W + (size_t)NCH * NCH * k);
      Ap = Bp;
      Bp = Cp;
    }
    silu_b16_k<<<GE, 256, 0, stream>>>(acc, b, hout);
  };
  run_layer(h1, h2, W2, b2, 12);
  run_layer(h2, h3, W3, b3, 10);

  // ---- layer 4: K=1, 32 -> 1, no bias ----
  final_kk<<<GR, 256, 0, stream>>>(h3, W4, out);
}

// Round 4
// 1919.467 us; speedup vs baseline: 2.0865x; 1.3592x over previous
//
#include <hip/hip_runtime.h>
#include <math.h>

#define NN 100000
#define EE 3200000
#define NCH 32
#define FILL_PASSES 8

typedef unsigned short ushortT;
typedef unsigned int uintT;

__device__ __forceinline__ float b2f(ushortT u) {
  return __uint_as_float(((uintT)u) << 16);
}
__device__ __forceinline__ ushortT f2b(float f) {
  uintT u = __float_as_uint(f);
  uintT r = u + 0x7fffu + ((u >> 16) & 1u);  // round-to-nearest-even
  return (ushortT)(r >> 16);
}
__device__ __forceinline__ uintT pack2(float x, float y) {
  return (uintT)f2b(x) | ((uintT)f2b(y) << 16);
}

// ---------------- setup kernels ----------------

__global__ void zero_i32_k(int* __restrict__ p, int n) {
  int i = blockIdx.x * blockDim.x + threadIdx.x;
  if (i < n) p[i] = 0;
}

__global__ void hist_k(const int* __restrict__ ei, int* __restrict__ cnt) {
  int t = blockIdx.x * blockDim.x + threadIdx.x;
  if (t * 4 >= EE) return;
  int4 r4 = ((const int4*)ei)[t];
  int4 c4 = ((const int4*)(ei + EE))[t];
  if (r4.x != c4.x) atomicAdd(&cnt[r4.x], 1);
  if (r4.y != c4.y) atomicAdd(&cnt[r4.y], 1);
  if (r4.z != c4.z) atomicAdd(&cnt[r4.z], 1);
  if (r4.w != c4.w) atomicAdd(&cnt[r4.w], 1);
}

__global__ void scan_block_k(const int* __restrict__ in, int* __restrict__ excl,
                             int* __restrict__ bsums, int n) {
  __shared__ int s[1024];
  int tid = threadIdx.x;
  int i = blockIdx.x * 1024 + tid;
  int v = (i < n) ? in[i] : 0;
  s[tid] = v;
  __syncthreads();
  for (int d = 1; d < 1024; d <<= 1) {
    int t = (tid >= d) ? s[tid - d] : 0;
    __syncthreads();
    s[tid] += t;
    __syncthreads();
  }
  if (i < n) excl[i] = s[tid] - v;
  if (tid == 1023) bsums[blockIdx.x] = s[1023];
}

__global__ void finalize_k(const int* __restrict__ cnt, int* __restrict__ rp,
                           int* __restrict__ cursor, const int* __restrict__ boffs,
                           float* __restrict__ dinv) {
  int i = blockIdx.x * blockDim.x + threadIdx.x;
  if (i >= NN) return;
  int v = rp[i] + boffs[i >> 10];
  rp[i] = v;
  cursor[i] = v;
  int c = cnt[i];
  dinv[i] = (c > 0) ? rsqrtf((float)c) : 0.f;
  if (i == NN - 1) rp[NN] = v + c;
}

// windowed scatter: rows in [lo,hi) only -> colc write window stays L2-resident
__global__ void fill_k(const int* __restrict__ ei, int* __restrict__ cursor,
                       int* __restrict__ colc, int lo, int hi) {
  int t = blockIdx.x * blockDim.x + threadIdx.x;
  if (t * 4 >= EE) return;
  int4 r4 = ((const int4*)ei)[t];
  int4 c4 = ((const int4*)(ei + EE))[t];
  if (r4.x != c4.x && r4.x >= lo && r4.x < hi) colc[atomicAdd(&cursor[r4.x], 1)] = c4.x;
  if (r4.y != c4.y && r4.y >= lo && r4.y < hi) colc[atomicAdd(&cursor[r4.y], 1)] = c4.y;
  if (r4.z != c4.z && r4.z >= lo && r4.z < hi) colc[atomicAdd(&cursor[r4.z], 1)] = c4.z;
  if (r4.w != c4.w && r4.w >= lo && r4.w < hi) colc[atomicAdd(&cursor[r4.w], 1)] = c4.w;
}

// zero the sentinel rows (row NN) of all gather tables; rows < NN only are
// written afterwards, so sentinels stay zero for the whole call.
__global__ void init_sent_k(uintT* Uh, uintT* Ua16, uintT* Ub16, float4* Uxf,
                            float4* Uaf, float4* Ubf) {
  int t = threadIdx.x;
  if (t < 16) {
    Uh[(size_t)NN * 16 + t] = 0u;
    Ua16[(size_t)NN * 16 + t] = 0u;
    Ub16[(size_t)NN * 16 + t] = 0u;
  }
  if (t == 0) {
    float4 z = make_float4(0.f, 0.f, 0.f, 0.f);
    Uxf[NN] = z; Uaf[NN] = z; Ubf[NN] = z;
  }
}

__global__ __launch_bounds__(256) void prescale_x_k(const float* __restrict__ x,
                                                    const float* __restrict__ dinv,
                                                    float4* __restrict__ Ux) {
  int i = blockIdx.x * blockDim.x + threadIdx.x;
  if (i >= NN) return;
  float di = dinv[i];
  Ux[i] = make_float4(di * x[3 * i], di * x[3 * i + 1], di * x[3 * i + 2], 0.f);
}

// ---------------- layer kernels ----------------

// 4 lanes per row, F=3. Gathers prescaled float4 U rows (pure sum).
// C = (FIRST ? L(B) : 2*L(B) - A) compact float3; Uout = dinv*C padded float4.
template <bool FIRST>
__global__ __launch_bounds__(256) void cheb_f3_k(
    const int* __restrict__ rp, const int* __restrict__ colc,
    const float* __restrict__ dinv, const float4* __restrict__ U,
    const float* __restrict__ A, float* __restrict__ C,
    float4* __restrict__ Uo) {
  int t4 = blockIdx.x * blockDim.x + threadIdx.x;
  int i = t4 >> 2, q = t4 & 3;
  if (i >= NN) return;
  int s = rp[i], e = rp[i + 1];
  float a0 = 0.f, a1 = 0.f, a2 = 0.f;
  for (int t = s + q; t < e; t += 16) {
#pragma unroll
    for (int u = 0; u < 4; ++u) {
      int tt = t + 4 * u;
      int cc = (tt < e) ? colc[tt] : NN;  // sentinel row NN is zero
      float4 r = U[cc];
      a0 += r.x; a1 += r.y; a2 += r.z;
    }
  }
  a0 += __shfl_xor(a0, 1); a1 += __shfl_xor(a1, 1); a2 += __shfl_xor(a2, 1);
  a0 += __shfl_xor(a0, 2); a1 += __shfl_xor(a1, 2); a2 += __shfl_xor(a2, 2);
  if (q == 0) {
    float di = dinv[i];
    float v0, v1, v2;
    if (FIRST) {
      v0 = -di * a0; v1 = -di * a1; v2 = -di * a2;
    } else {
      v0 = fmaf(-2.f * di, a0, -A[3 * i + 0]);
      v1 = fmaf(-2.f * di, a1, -A[3 * i + 1]);
      v2 = fmaf(-2.f * di, a2, -A[3 * i + 2]);
    }
    C[3 * i + 0] = v0; C[3 * i + 1] = v1; C[3 * i + 2] = v2;
    Uo[i] = make_float4(di * v0, di * v1, di * v2, 0.f);
  }
}

// Layer-1 batched GEMM over all 24 T-planes + bias + SiLU -> bf16 h + prescaled Uh.
__global__ __launch_bounds__(256) void gemm_l1_k(const float* __restrict__ x,
                                                 const float* __restrict__ Tall,
                                                 const float* __restrict__ W1,
                                                 const float* __restrict__ b1,
                                                 const float* __restrict__ dinv,
                                                 ushortT* __restrict__ h1,
                                                 ushortT* __restrict__ Uh) {
  __shared__ float Wl[24 * 96];
  for (int t = threadIdx.x; t < 24 * 96; t += 256) Wl[t] = W1[t];
  __syncthreads();
  int t = blockIdx.x * blockDim.x + threadIdx.x;
  if (t >= NN * NCH) return;
  int i = t >> 5, j = t & 31;
  float g = b1[j];
  g = fmaf(x[i * 3 + 0], Wl[j],
      fmaf(x[i * 3 + 1], Wl[32 + j], fmaf(x[i * 3 + 2], Wl[64 + j], g)));
#pragma unroll
  for (int k = 1; k < 24; ++k) {
    const float* Tp = Tall + ((size_t)(k - 1) * NN + i) * 3;
    g = fmaf(Tp[0], Wl[k * 96 + j],
        fmaf(Tp[1], Wl[k * 96 + 32 + j], fmaf(Tp[2], Wl[k * 96 + 64 + j], g)));
  }
  float sv = g / (1.f + expf(-g));
  h1[t] = f2b(sv);
  Uh[t] = f2b(dinv[i] * sv);
}

// acc = in(N x 32, bf16) @ W(32 x 32, f32); row loaded as 16 dwords
__global__ __launch_bounds__(256) void gemm_k0_b16_k(const ushortT* __restrict__ in,
                                                     const float* __restrict__ W,
                                                     float* __restrict__ acc) {
  __shared__ float Wl[NCH * NCH];
  for (int t = threadIdx.x; t < NCH * NCH; t += 256) Wl[t] = W[t];
  __syncthreads();
  int t = blockIdx.x * blockDim.x + threadIdx.x;
  if (t >= NN * NCH) return;
  int i = t >> 5, j = t & 31;
  const uintT* bi = (const uintT*)in + (size_t)i * 16;
  float g = 0.f;
#pragma unroll
  for (int p = 0; p < 16; ++p) {
    uintT u = bi[p];
    g = fmaf(__uint_as_float(u << 16), Wl[(2 * p) * NCH + j], g);
    g = fmaf(__uint_as_float(u & 0xffff0000u), Wl[(2 * p + 1) * NCH + j], g);
  }
  acc[t] = g;
}

// One wave per row, quarter-wave dword gathers from prescaled bf16 U table.
// C = (FIRST ? L : 2L - A) bf16; Uo = dinv*C bf16; acc += C @ Wk.
template <bool FIRST>
__global__ __launch_bounds__(256) void cheb_b16_k(
    const int* __restrict__ rp, const int* __restrict__ colc,
    const float* __restrict__ dinv, const uintT* __restrict__ U,
    const uintT* __restrict__ A, uintT* __restrict__ C,
    uintT* __restrict__ Uo, float* __restrict__ acc,
    const float* __restrict__ Wk) {
  __shared__ float Wl[NCH * NCH];
  for (int t = threadIdx.x; t < NCH * NCH; t += 256) Wl[t] = Wk[t];
  __syncthreads();
  int tid = threadIdx.x;
  int wid = tid >> 6, lane = tid & 63;
  int p = lane & 15, h = lane >> 4;
  int nwaves = gridDim.x * 4;
  for (int i = blockIdx.x * 4 + wid; i < NN; i += nwaves) {
    int s = rp[i], e = rp[i + 1];
    float ax = 0.f, ay = 0.f;
    for (int base = s; base < e; base += 64) {
      int idx = base + lane;
      int cl = (idx < e) ? colc[idx] : NN;  // sentinel -> zero row
      int m = e - base;
      if (m > 64) m = 64;
      for (int jj = 0; jj < m; jj += 16) {
#pragma unroll
        for (int q = 0; q < 4; ++q) {
          int j = jj + 4 * q + h;
          int cj = __shfl(cl, j);
          uintT r = U[(size_t)cj * 16 + p];
          ax += __uint_as_float(r << 16);
          ay += __uint_as_float(r & 0xffff0000u);
        }
      }
    }
    ax += __shfl_down(ax, 32); ay += __shfl_down(ay, 32);
    ax += __shfl_down(ax, 16); ay += __shfl_down(ay, 16);
    // lanes 0..15 hold channel-pair sums
    float di = dinv[i];
    float vx, vy;
    if (FIRST) {
      vx = -di * ax; vy = -di * ay;
    } else {
      uintT au = A[(size_t)i * 16 + p];
      vx = fmaf(-2.f * di, ax, -__uint_as_float(au << 16));
      vy = fmaf(-2.f * di, ay, -__uint_as_float(au & 0xffff0000u));
    }
    if (lane < 16) {
      C[(size_t)i * 16 + p] = pack2(vx, vy);
      Uo[(size_t)i * 16 + p] = pack2(di * vx, di * vy);
    }
    // fused acc += v @ Wk (v valid on lanes 0..15 as channel pairs)
    int hf = lane >> 5, j = lane & 31;
    float g = 0.f;
#pragma unroll
    for (int t = 0; t < 8; ++t) {
      int tt = hf * 8 + t;
      float vxx = __shfl(vx, tt);
      float vyy = __shfl(vy, tt);
      g = fmaf(vxx, Wl[(2 * tt) * NCH + j], g);
      g = fmaf(vyy, Wl[(2 * tt + 1) * NCH + j], g);
    }
    g += __shfl_down(g, 32);
    if (hf == 0) acc[(size_t)i * NCH + j] += g;
  }
}

__global__ __launch_bounds__(256) void silu_b16_k(const float* __restrict__ a,
                                                  const float* __restrict__ b,
                                                  const float* __restrict__ dinv,
                                                  ushortT* __restrict__ h,
                                                  ushortT* __restrict__ Uh) {
  int t = blockIdx.x * blockDim.x + threadIdx.x;
  if (t >= NN * NCH) return;
  float v = a[t] + b[t & 31];
  float sv = v / (1.f + expf(-v));
  h[t] = f2b(sv);
  Uh[t] = f2b(dinv[t >> 5] * sv);
}

__global__ __launch_bounds__(256) void final_kk(const ushortT* __restrict__ h,
                                                const float* __restrict__ W4,
                                                float* __restrict__ out) {
  __shared__ float Wl[32];
  if (threadIdx.x < 32) Wl[threadIdx.x] = W4[threadIdx.x];
  __syncthreads();
  int i = blockIdx.x * blockDim.x + threadIdx.x;
  if (i >= NN) return;
  const uintT* hr = (const uintT*)h + (size_t)i * 16;
  float g = 0.f;
#pragma unroll
  for (int p = 0; p < 16; ++p) {
    uintT u = hr[p];
    g = fmaf(__uint_as_float(u << 16), Wl[2 * p], g);
    g = fmaf(__uint_as_float(u & 0xffff0000u), Wl[2 * p + 1], g);
  }
  out[i] = g;
}

// ---------------- host ----------------

extern "C" void kernel_launch(void* const* d_in, const int* in_sizes, int n_in,
                              void* d_out, int out_size, void* d_ws, size_t ws_size,
                              hipStream_t stream) {
  const float* x = (const float*)d_in[0];
  const int* ei = (const int*)d_in[1];
  const float* W1 = (const float*)d_in[4];
  const float* b1 = (const float*)d_in[5];
  const float* W2 = (const float*)d_in[6];
  const float* b2 = (const float*)d_in[7];
  const float* W3 = (const float*)d_in[8];
  const float* b3 = (const float*)d_in[9];
  const float* W4 = (const float*)d_in[10];
  float* out = (float*)d_out;

  char* ws = (char*)d_ws;
  size_t off = 0;
  auto alloc = [&](size_t bytes) {
    void* p = ws + off;
    off += (bytes + 255) & ~(size_t)255;
    return p;
  };
  int* cnt = (int*)alloc((size_t)NN * 4);
  int* rp = (int*)alloc(((size_t)NN + 1) * 4);
  int* cursor = (int*)alloc((size_t)NN * 4);
  int* bsums = (int*)alloc(1024 * 4);
  int* boffs = (int*)alloc(1024 * 4);
  float* dinv = (float*)alloc((size_t)NN * 4);
  int* colc = (int*)alloc((size_t)EE * 4);
  float4* Uxf = (float4*)alloc(((size_t)NN + 1) * 16);
  float4* Uaf = (float4*)alloc(((size_t)NN + 1) * 16);
  float4* Ubf = (float4*)alloc(((size_t)NN + 1) * 16);
  ushortT* Uh = (ushortT*)alloc(((size_t)NN + 1) * 64);
  ushortT* Ua16 = (ushortT*)alloc(((size_t)NN + 1) * 64);
  ushortT* Ub16 = (ushortT*)alloc(((size_t)NN + 1) * 64);
  ushortT* h1 = (ushortT*)alloc((size_t)NN * NCH * 2);
  ushortT* h2 = (ushortT*)alloc((size_t)NN * NCH * 2);
  float* Tall = (float*)alloc((size_t)23 * NN * 3 * 4);  // 27.6 MB, dead after gemm_l1
  ushortT* tC = (ushortT*)alloc((size_t)NN * NCH * 2);
  // overlays into Tall (live only during layers 2/3)
  float* acc = Tall;                                      // 12.8 MB
  ushortT* tA = (ushortT*)((char*)Tall + 12800000);       // 6.4 MB
  ushortT* tB = (ushortT*)((char*)Tall + 19200000);       // 6.4 MB
  ushortT* h3 = h1;                                       // h1 dead by then
  (void)ws_size; (void)in_sizes; (void)n_in; (void)out_size;

  // ---- CSR build ----
  zero_i32_k<<<(NN + 255) / 256, 256, 0, stream>>>(cnt, NN);
  hist_k<<<(EE / 4 + 255) / 256, 256, 0, stream>>>(ei, cnt);
  int nb = (NN + 1023) / 1024;
  scan_block_k<<<nb, 1024, 0, stream>>>(cnt, rp, bsums, NN);
  scan_block_k<<<1, 1024, 0, stream>>>(bsums, boffs, bsums, nb);
  finalize_k<<<(NN + 255) / 256, 256, 0, stream>>>(cnt, rp, cursor, boffs, dinv);
  {
    int step = (NN + FILL_PASSES - 1) / FILL_PASSES;
    for (int p = 0; p < FILL_PASSES; ++p) {
      int lo = p * step;
      int hi = (lo + step < NN) ? lo + step : NN;
      fill_k<<<(EE / 4 + 255) / 256, 256, 0, stream>>>(ei, cursor, colc, lo, hi);
    }
  }
  init_sent_k<<<1, 64, 0, stream>>>((uintT*)Uh, (uintT*)Ua16, (uintT*)Ub16, Uxf, Uaf, Ubf);

  const int GB = 2048;                     // wave-per-row grid (grid-stride)
  const int GE = (NN * NCH + 255) / 256;   // elementwise grids
  const int GR = (NN + 255) / 256;         // row grids
  const int GR4 = (NN * 4 + 255) / 256;    // quad-per-row grid

  auto Tp = [&](int k) { return Tall + (size_t)(k - 1) * NN * 3; };

  // ---- layer 1: K=24, F=3 -> 32 ----
  prescale_x_k<<<GR, 256, 0, stream>>>(x, dinv, Uxf);
  cheb_f3_k<true><<<GR4, 256, 0, stream>>>(rp, colc, dinv, Uxf, nullptr, Tp(1), Uaf);
  for (int k = 2; k < 24; ++k) {
    const float4* Ug = (k & 1) ? Ubf : Uaf;
    float4* Uw = (k & 1) ? Uaf : Ubf;
    const float* Apf = (k == 2) ? x : Tp(k - 2);
    cheb_f3_k<false><<<GR4, 256, 0, stream>>>(rp, colc, dinv, Ug, Apf, Tp(k), Uw);
  }
  gemm_l1_k<<<GE, 256, 0, stream>>>(x, Tall, W1, b1, dinv, h1, Uh);

  // ---- layers 2 & 3: K=12 / K=10, F=32 -> 32, bf16 prescaled-gather ----
  auto run_layer = [&](const ushortT* in, ushortT* hout, ushortT* Uhout,
                       const float* W, const float* b, int K) {
    gemm_k0_b16_k<<<GE, 256, 0, stream>>>(in, W, acc);
    cheb_b16_k<true><<<GB, 256, 0, stream>>>(rp, colc, dinv, (const uintT*)Uh,
                                             nullptr, (uintT*)tA, (uintT*)Ua16,
                                             acc, W + NCH * NCH);
    const uintT* Ap = (const uintT*)in;
    ushortT* Cprev = tA;
    ushortT* cyc[3] = {tB, tC, tA};
    for (int k = 2; k < K; ++k) {
      ushortT* Cp = cyc[(k - 2) % 3];
      const uintT* Ug = (k & 1) ? (const uintT*)Ub16 : (const uintT*)Ua16;
      uintT* Uw = (k & 1) ? (uintT*)Ua16 : (uintT*)Ub16;
      cheb_b16_k<false><<<GB, 256, 0, stream>>>(rp, colc, dinv, Ug, Ap,
                                                (uintT*)Cp, Uw, acc,
                                                W + (size_t)NCH * NCH * k);
      Ap = (const uintT*)Cprev;
      Cprev = Cp;
    }
    silu_b16_k<<<GE, 256, 0, stream>>>(acc, b, dinv, hout, Uhout);
  };
  run_layer(h1, h2, Uh, W2, b2, 12);
  run_layer(h2, h3, Uh, W3, b3, 10);

  // ---- layer 4: K=1, 32 -> 1, no bias ----
  final_kk<<<GR, 256, 0, stream>>>(h3, W4, out);
}